// Round 4
// baseline (577.226 us; speedup 1.0000x reference)
//
#include <hip/hip_runtime.h>
#include <math.h>

#define N_ANT 64
#define BATCH 131072
#define NSTEPS 63   // 31 internal softmax units + 32 leaf groups, DFS preorder
#define TPB 128

typedef float v2f __attribute__((ext_vector_type(2)));

// Forced VOP3P dual-FP32 FMA: acc = va * sb + acc.
// acc, va in VGPR pairs; sb in an SGPR pair (weights are wave-uniform, and
// one scalar source per VALU instruction is architecturally legal).
#define PKFMA_VS(acc, va, sb) \
    asm("v_pk_fma_f32 %0, %1, %2, %0" : "+v"(acc) : "v"(va), "s"(sb))

static __device__ __forceinline__ float fast_rcp(float x) {
#if __has_builtin(__builtin_amdgcn_rcpf)
    return __builtin_amdgcn_rcpf(x);
#else
    return 1.0f / x;
#endif
}

// Advance DFS-preorder state over the complete binary tree.
// Internal units: l=0..4 (node n at layer l). Leaf groups: l==5 (group n).
static __device__ __forceinline__ void dfs_next(int& l, int& n) {
    if (l < 5) { l = l + 1; n = 2 * n; }
    else {
        while (n & 1) { n >>= 1; l--; }
        n += 1;
    }
}

// Build combined real weight buffer in DFS-step order.
// Unit s occupies W[s*256 .. s*256+255]:
//   [  0.. 63] col0 w_re[a]   [ 64..127] col0 w_im[a]
//   [128..191] col1 w_re[a]   [192..255] col1 w_im[a]
__global__ void fill_weights(const float* __restrict__ t0, const float* __restrict__ t1,
                             const float* __restrict__ t2, const float* __restrict__ t3,
                             const float* __restrict__ t4, float* __restrict__ W) {
    const int s = blockIdx.x;
    const int a = threadIdx.x;  // antenna index 0..63
    int l = 0, n = 0;
    for (int i = 0; i < s; ++i) dfs_next(l, n);
    float* w = W + s * 256;
    const float inv = 0.125f;  // 1/sqrt(64)
    if (l < 5) {
        const float* th = (l == 0) ? t0 : (l == 1) ? t1 : (l == 2) ? t2 : (l == 3) ? t3 : t4;
        float th0 = th[(n * N_ANT + a) * 2 + 0];
        float th1 = th[(n * N_ANT + a) * 2 + 1];
        float s0, c0, s1, c1;
        sincosf(th0, &s0, &c0);
        sincosf(th1, &s1, &c1);
        w[0   + a] = c0 * inv;  w[64  + a] = s0 * inv;
        w[128 + a] = c1 * inv;  w[192 + a] = s1 * inv;
    } else {
        // Leaf DFT codebook columns 2n, 2n+1 (numpy computes in float64 then casts).
        const double step = (cos(M_PI - 1e-6) - 1.0) / 63.0;
        for (int k = 0; k < 2; ++k) {
            int c = 2 * n + k;
            double cosaz = 1.0 + (double)c * step;
            double ph = M_PI * (double)a * cosaz;
            w[128 * k + 0  + a] = (float)(cos(ph) * 0.125);
            w[128 * k + 64 + a] = (float)(sin(ph) * 0.125);
        }
    }
}

// waves_per_eu(2,2): grid supplies exactly 2 waves/SIMD (131072 threads on 256
// CUs); clamping min=max=2 gives the allocator the full 256-VGPR budget so the
// 128-float x row has no pressure motive to spill into AGPRs (R2/R3 failure).
__global__ __launch_bounds__(TPB)
__attribute__((amdgpu_waves_per_eu(2, 2)))
void beam_tree(const float* __restrict__ x,
               const float* __restrict__ W,
               float* __restrict__ out) {
    // Output staging: row stride 66 words; flushed coalesced at the end.
    __shared__ float stg[TPB * 66];
    // Per-thread 5-level DFS probability stack; stride 11 (odd) -> 2 lanes/bank.
    __shared__ float stk[TPB * 11];

    const int tid = threadIdx.x;
    const int e = blockIdx.x * TPB + tid;

    // x row: [re(0..63) | im(0..63)] as 32+32 v2f pairs, kept in VGPRs.
    const v2f* px = (const v2f*)(x + (size_t)e * 128);
    v2f xr[32], xi[32];
#pragma unroll
    for (int j = 0; j < 32; ++j) xr[j] = px[j];
#pragma unroll
    for (int j = 0; j < 32; ++j) xi[j] = px[32 + j];

    float* st = stk + tid * 11;
    float* sr = stg + tid * 66;

    int l = 0, n = 0, g = 0;
#pragma unroll 1
    for (int s = 0; s < NSTEPS; ++s) {
        const v2f* w0r = (const v2f*)(W + s * 256);  // wave-uniform -> SGPRs
        const v2f* w0i = w0r + 32;
        const v2f* w1r = w0r + 64;
        const v2f* w1i = w0r + 96;
        v2f arr = {0.f, 0.f}, ari = {0.f, 0.f}, air = {0.f, 0.f}, aii = {0.f, 0.f};
        v2f brr = {0.f, 0.f}, bri = {0.f, 0.f}, bir = {0.f, 0.f}, bii = {0.f, 0.f};
#pragma unroll 8
        for (int t = 0; t < 32; ++t) {
            v2f wr0 = w0r[t], wi0 = w0i[t], wr1 = w1r[t], wi1 = w1i[t];
            PKFMA_VS(arr, xr[t], wr0);
            PKFMA_VS(air, xi[t], wr0);
            PKFMA_VS(ari, xr[t], wi0);
            PKFMA_VS(aii, xi[t], wi0);
            PKFMA_VS(brr, xr[t], wr1);
            PKFMA_VS(bir, xi[t], wr1);
            PKFMA_VS(bri, xr[t], wi1);
            PKFMA_VS(bii, xi[t], wi1);
        }
        // complex dot: re = xr.wre - xi.wim ; im = xr.wim + xi.wre
        float y0r = (arr.x + arr.y) - (aii.x + aii.y);
        float y0i = (ari.x + ari.y) + (air.x + air.y);
        float y1r = (brr.x + brr.y) - (bii.x + bii.y);
        float y1i = (bri.x + bri.y) + (bir.x + bir.y);
        float g0 = fmaf(y0r, y0r, y0i * y0i);
        float g1 = fmaf(y1r, y1r, y1i * y1i);
        // 2-way softmax (max-subtracted, matches jax.nn.softmax)
        float m  = fmaxf(g0, g1);
        float e0 = __expf(g0 - m);
        float e1 = __expf(g1 - m);
        float inv = fast_rcp(e0 + e1);
        float p0 = e0 * inv, p1 = e1 * inv;

        float pme = (l == 0) ? 1.0f : st[(l - 1) * 2 + (n & 1)];
        if (l < 5) {
            st[l * 2 + 0] = pme * p0;
            st[l * 2 + 1] = pme * p1;
        } else {
            *(v2f*)(sr + 2 * g) = (v2f){pme * p0, pme * p1};  // ds_write_b64
            g++;
        }
        dfs_next(l, n);
    }

    // Coalesced flush: block's 128 rows x 64 floats = 32 KB contiguous in out.
    __syncthreads();
    float4* ob = (float4*)(out + (size_t)blockIdx.x * TPB * 64);
#pragma unroll
    for (int k = 0; k < 16; ++k) {
        int fidx = k * TPB + tid;        // float4 index within block tile
        int row = fidx >> 4;             // 16 float4 per row
        int col = (fidx & 15) * 4;
        const float* sp = stg + row * 66 + col;
        v2f a = *(const v2f*)(sp);
        v2f b = *(const v2f*)(sp + 2);
        ob[fidx] = make_float4(a.x, a.y, b.x, b.y);
    }
}

extern "C" void kernel_launch(void* const* d_in, const int* in_sizes, int n_in,
                              void* d_out, int out_size, void* d_ws, size_t ws_size,
                              hipStream_t stream) {
    const float* x  = (const float*)d_in[0];
    const float* t0 = (const float*)d_in[1];
    const float* t1 = (const float*)d_in[2];
    const float* t2 = (const float*)d_in[3];
    const float* t3 = (const float*)d_in[4];
    const float* t4 = (const float*)d_in[5];
    float* W = (float*)d_ws;  // 63*256*4 = 64.5 KB, rebuilt every call (ws re-poisoned)

    fill_weights<<<dim3(NSTEPS), dim3(N_ANT), 0, stream>>>(t0, t1, t2, t3, t4, W);
    beam_tree<<<dim3(BATCH / TPB), dim3(TPB), 0, stream>>>(x, W, (float*)d_out);
}

// Round 5
// 234.054 us; speedup vs baseline: 2.4662x; 2.4662x over previous
//
#include <hip/hip_runtime.h>
#include <math.h>

#define N_ANT 64
#define BATCH 131072
#define NSTEPS 63   // 31 internal softmax units + 32 leaf groups, DFS preorder
#define TPB 256     // 64 elements/block, 4 lanes per element
#define ELEMS 64
#define CH0 32      // units in LDS chunk 0
#define CH1 31      // units in LDS chunk 1

typedef float v2f __attribute__((ext_vector_type(2)));
typedef float v4f __attribute__((ext_vector_type(4)));

// All-VGPR packed FMA: acc(v-pair) += a(v-pair) * b(v-pair).
// R4's failure was the "s" constraint under register pressure; with per-lane
// state ~75 VGPRs this is safe and guarantees pk formation.
#define PKFMA(acc, a, b) \
    asm("v_pk_fma_f32 %0, %1, %2, %0" : "+v"(acc) : "v"(a), "v"(b))

static __device__ __forceinline__ float fast_rcp(float x) {
#if __has_builtin(__builtin_amdgcn_rcpf)
    return __builtin_amdgcn_rcpf(x);
#else
    return 1.0f / x;
#endif
}

// Sum a value across the 4 lanes of a quad via DPP butterflies (xor1, xor2).
// All 4 lanes end with bit-identical sums (same grouping order).
static __device__ __forceinline__ float qsum(float v) {
    float a = __int_as_float(__builtin_amdgcn_update_dpp(
        0, __float_as_int(v), 0xB1 /*quad_perm [1,0,3,2]*/, 0xF, 0xF, true));
    v += a;
    float b = __int_as_float(__builtin_amdgcn_update_dpp(
        0, __float_as_int(v), 0x4E /*quad_perm [2,3,0,1]*/, 0xF, 0xF, true));
    v += b;
    return v;
}

// Advance DFS-preorder state over the complete binary tree.
// Internal units: l=0..4 (node n at layer l). Leaf groups: l==5 (group n).
static __device__ __forceinline__ void dfs_next(int& l, int& n) {
    if (l < 5) { l = l + 1; n = 2 * n; }
    else {
        while (n & 1) { n >>= 1; l--; }
        n += 1;
    }
}

// Build combined real weight buffer in DFS-step order.
// Unit s occupies W[s*256 .. s*256+255]:
//   [  0.. 63] col0 w_re[a]   [ 64..127] col0 w_im[a]
//   [128..191] col1 w_re[a]   [192..255] col1 w_im[a]
__global__ void fill_weights(const float* __restrict__ t0, const float* __restrict__ t1,
                             const float* __restrict__ t2, const float* __restrict__ t3,
                             const float* __restrict__ t4, float* __restrict__ W) {
    const int s = blockIdx.x;
    const int a = threadIdx.x;  // antenna index 0..63
    int l = 0, n = 0;
    for (int i = 0; i < s; ++i) dfs_next(l, n);
    float* w = W + s * 256;
    const float inv = 0.125f;  // 1/sqrt(64)
    if (l < 5) {
        const float* th = (l == 0) ? t0 : (l == 1) ? t1 : (l == 2) ? t2 : (l == 3) ? t3 : t4;
        float th0 = th[(n * N_ANT + a) * 2 + 0];
        float th1 = th[(n * N_ANT + a) * 2 + 1];
        float s0, c0, s1, c1;
        sincosf(th0, &s0, &c0);
        sincosf(th1, &s1, &c1);
        w[0   + a] = c0 * inv;  w[64  + a] = s0 * inv;
        w[128 + a] = c1 * inv;  w[192 + a] = s1 * inv;
    } else {
        // Leaf DFT codebook columns 2n, 2n+1 (numpy computes in float64 then casts).
        const double step = (cos(M_PI - 1e-6) - 1.0) / 63.0;
        for (int k = 0; k < 2; ++k) {
            int c = 2 * n + k;
            double cosaz = 1.0 + (double)c * step;
            double ph = M_PI * (double)a * cosaz;
            w[128 * k + 0  + a] = (float)(cos(ph) * 0.125);
            w[128 * k + 64 + a] = (float)(sin(ph) * 0.125);
        }
    }
}

__global__ __launch_bounds__(TPB) void beam_tree(const float* __restrict__ x,
                                                 const float* __restrict__ W,
                                                 float* __restrict__ out) {
    // Weight chunk buffer (32 units x 256 floats = 32 KB), 16B-aligned.
    __shared__ v4f wbuf4[CH0 * 64];
    // Output staging: 64 elements x stride 66 (16.9 KB).
    __shared__ float stg[ELEMS * 66];
    // Per-element 5-level DFS stack, stride 13 (3.3 KB).
    __shared__ float stk[ELEMS * 13];

    float* wbuf = (float*)wbuf4;
    const int tid = threadIdx.x;
    const int k = tid & 3;          // lane within quad = antenna chunk
    const int el = tid >> 2;        // element within block (0..63)
    const int elem = blockIdx.x * ELEMS + el;
    const bool writer = (k == 0);

    // Load this lane's 16 antennas: xr at [k*16..], xi at [64+k*16..].
    const v4f* pxr = (const v4f*)(x + (size_t)elem * 128 + k * 16);
    const v4f* pxi = (const v4f*)(x + (size_t)elem * 128 + 64 + k * 16);
    v2f xrp[8], xip[8];
#pragma unroll
    for (int j = 0; j < 4; ++j) {
        v4f v = pxr[j]; xrp[2 * j] = v.xy; xrp[2 * j + 1] = v.zw;
        v4f u = pxi[j]; xip[2 * j] = u.xy; xip[2 * j + 1] = u.zw;
    }

    float* st = stk + el * 13;
    float* sr = stg + el * 66;
    const int k16 = k * 16;

    int l = 0, n = 0, g = 0;

    for (int chunk = 0; chunk < 2; ++chunk) {
        const int s0 = (chunk == 0) ? 0 : CH0;
        const int units = (chunk == 0) ? CH0 : CH1;

        // Stage chunk weights into LDS (coalesced float4 copies).
        if (chunk == 1) __syncthreads();  // everyone done reading chunk 0
        {
            const v4f* src = (const v4f*)(W + s0 * 256);
            const int nvec = units * 64;
#pragma unroll 1
            for (int v = tid; v < nvec; v += TPB) wbuf4[v] = src[v];
        }
        __syncthreads();

#pragma unroll 1
        for (int u = 0; u < units; ++u) {
            const float* wu = wbuf + u * 256 + k16;
            v2f rr0 = {0, 0}, ri0 = {0, 0}, ir0 = {0, 0}, ii0 = {0, 0};
            v2f rr1 = {0, 0}, ri1 = {0, 0}, ir1 = {0, 0}, ii1 = {0, 0};
#pragma unroll
            for (int t = 0; t < 4; ++t) {
                v4f w0r = *(const v4f*)(wu + t * 4);
                v4f w0i = *(const v4f*)(wu + 64 + t * 4);
                v4f w1r = *(const v4f*)(wu + 128 + t * 4);
                v4f w1i = *(const v4f*)(wu + 192 + t * 4);
                v2f xa = xrp[2 * t], xb = xrp[2 * t + 1];
                v2f ya = xip[2 * t], yb = xip[2 * t + 1];
                v2f w0ra = w0r.xy, w0rb = w0r.zw;
                v2f w0ia = w0i.xy, w0ib = w0i.zw;
                v2f w1ra = w1r.xy, w1rb = w1r.zw;
                v2f w1ia = w1i.xy, w1ib = w1i.zw;
                PKFMA(rr0, xa, w0ra); PKFMA(rr0, xb, w0rb);
                PKFMA(ri0, xa, w0ia); PKFMA(ri0, xb, w0ib);
                PKFMA(ir0, ya, w0ra); PKFMA(ir0, yb, w0rb);
                PKFMA(ii0, ya, w0ia); PKFMA(ii0, yb, w0ib);
                PKFMA(rr1, xa, w1ra); PKFMA(rr1, xb, w1rb);
                PKFMA(ri1, xa, w1ia); PKFMA(ri1, xb, w1ib);
                PKFMA(ir1, ya, w1ra); PKFMA(ir1, yb, w1rb);
                PKFMA(ii1, ya, w1ia); PKFMA(ii1, yb, w1ib);
            }
            // complex dot partials over this lane's 16 antennas
            v2f t0r = rr0 - ii0, t0i = ri0 + ir0;
            v2f t1r = rr1 - ii1, t1i = ri1 + ir1;
            // quad reduction -> full dots, identical in all 4 lanes
            float y0r = qsum(t0r.x + t0r.y);
            float y0i = qsum(t0i.x + t0i.y);
            float y1r = qsum(t1r.x + t1r.y);
            float y1i = qsum(t1i.x + t1i.y);
            float g0 = fmaf(y0r, y0r, y0i * y0i);
            float g1 = fmaf(y1r, y1r, y1i * y1i);
            // 2-way softmax (max-subtracted, matches jax.nn.softmax)
            float m  = fmaxf(g0, g1);
            float e0 = __expf(g0 - m);
            float e1 = __expf(g1 - m);
            float inv = fast_rcp(e0 + e1);
            float p0 = e0 * inv, p1 = e1 * inv;

            float pme = (l == 0) ? 1.0f : st[(l - 1) * 2 + (n & 1)];
            if (l < 5) {
                if (writer) {
                    st[l * 2 + 0] = pme * p0;
                    st[l * 2 + 1] = pme * p1;
                }
                __builtin_amdgcn_wave_barrier();  // LDS write->read same wave order
            } else {
                if (writer) *(v2f*)(sr + 2 * g) = (v2f){pme * p0, pme * p1};
                g++;
            }
            dfs_next(l, n);
        }
    }

    // Coalesced flush: 64 rows x 64 floats = 16 KB contiguous in out.
    __syncthreads();
    v4f* ob = (v4f*)(out + (size_t)blockIdx.x * ELEMS * 64);
#pragma unroll
    for (int q = 0; q < 4; ++q) {
        int fidx = q * TPB + tid;        // float4 index within block tile
        int row = fidx >> 4;             // 16 float4 per row
        int col = (fidx & 15) * 4;
        const float* sp = stg + row * 66 + col;
        v2f a = *(const v2f*)(sp);
        v2f b = *(const v2f*)(sp + 2);
        ob[fidx] = (v4f){a.x, a.y, b.x, b.y};
    }
}

extern "C" void kernel_launch(void* const* d_in, const int* in_sizes, int n_in,
                              void* d_out, int out_size, void* d_ws, size_t ws_size,
                              hipStream_t stream) {
    const float* x  = (const float*)d_in[0];
    const float* t0 = (const float*)d_in[1];
    const float* t1 = (const float*)d_in[2];
    const float* t2 = (const float*)d_in[3];
    const float* t3 = (const float*)d_in[4];
    const float* t4 = (const float*)d_in[5];
    float* W = (float*)d_ws;  // 63*256*4 = 64.5 KB, rebuilt every call

    fill_weights<<<dim3(NSTEPS), dim3(N_ANT), 0, stream>>>(t0, t1, t2, t3, t4, W);
    beam_tree<<<dim3(BATCH / ELEMS), dim3(TPB), 0, stream>>>(x, W, (float*)d_out);
}

// Round 6
// 179.118 us; speedup vs baseline: 3.2226x; 1.3067x over previous
//
#include <hip/hip_runtime.h>
#include <math.h>

#define N_ANT 64
#define BATCH 131072
#define NSTEPS 63      // 31 internal softmax units + 32 leaf groups, DFS preorder
#define TPB 256        // 4 waves; wave m-tile = 16 rows; block m-tile = 64 rows
#define GSTRIDE 129    // gains LDS row stride (floats): (el + c) banks, <=2-way
#define PSTRIDE 66     // pout LDS row stride

typedef float f32x4 __attribute__((ext_vector_type(4)));
typedef float v2f   __attribute__((ext_vector_type(2)));
typedef _Float16 f16x8 __attribute__((ext_vector_type(8)));

static __device__ __forceinline__ float fast_rcp(float x) {
#if __has_builtin(__builtin_amdgcn_rcpf)
    return __builtin_amdgcn_rcpf(x);
#else
    return 1.0f / x;
#endif
}

// Advance DFS-preorder state over the complete binary tree.
// Internal units: l=0..4 (node n at layer l). Leaf groups: l==5 (group n).
static __device__ __forceinline__ void dfs_next(int& l, int& n) {
    if (l < 5) { l = l + 1; n = 2 * n; }
    else {
        while (n & 1) { n >>= 1; l--; }
        n += 1;
    }
}

// Build B operand (128 K x 256 N real, N 252..255 zero-padded) as TWO fp16
// splits (B = B1 + B2 exactly to ~2^-22), prepacked in MFMA B-fragment order:
//   slot t = ((ntile*4 + kstep)*64 + lane), 8 contiguous fp16 per slot,
//   element j of slot maps to B[k = kstep*32 + (lane>>4)*8 + j][n = ntile*16 + (lane&15)].
// Column semantics: complex col c = n>>1 (unit s = c>>1 in DFS order, child
// kidx = c&1); real col n = 2c   -> [wr ; -wi] over k (antenna a = k&63)
//                  real col n = 2c+1 -> [wi ;  wr].
__global__ void fill_B(const float* __restrict__ t0, const float* __restrict__ t1,
                       const float* __restrict__ t2, const float* __restrict__ t3,
                       const float* __restrict__ t4,
                       _Float16* __restrict__ B1p, _Float16* __restrict__ B2p) {
    const int t = blockIdx.x * 256 + threadIdx.x;   // 0..4095
    const int L = t & 63;
    const int kstep = (t >> 6) & 3;
    const int ntile = t >> 8;
    const int n = ntile * 16 + (L & 15);
    const int kbase = kstep * 32 + (L >> 4) * 8;

    f16x8 h1 = {0,0,0,0,0,0,0,0}, h2 = {0,0,0,0,0,0,0,0};
    if (n < 252) {
        const int c = n >> 1, part = n & 1;
        const int s = c >> 1, kidx = c & 1;
        int l = 0, nn = 0;
        for (int i = 0; i < s; ++i) dfs_next(l, nn);
#pragma unroll
        for (int j = 0; j < 8; ++j) {
            const int k = kbase + j;
            const int a = k & 63;       // antenna
            const int hi = k >> 6;      // 0: first 64 K-rows, 1: second
            float wr, wi;
            if (l < 5) {
                const float* th = (l == 0) ? t0 : (l == 1) ? t1 : (l == 2) ? t2
                                 : (l == 3) ? t3 : t4;
                float theta = th[(nn * N_ANT + a) * 2 + kidx];
                float sn, cs;
                sincosf(theta, &sn, &cs);
                wr = cs * 0.125f; wi = sn * 0.125f;
            } else {
                // Leaf DFT codebook beam b (fp64, matches numpy reference).
                const int b = 2 * nn + kidx;
                const double step = (cos(M_PI - 1e-6) - 1.0) / 63.0;
                double cosaz = 1.0 + (double)b * step;
                double ph = M_PI * (double)a * cosaz;
                wr = (float)(cos(ph) * 0.125);
                wi = (float)(sin(ph) * 0.125);
            }
            float v = (part == 0) ? (hi == 0 ? wr : -wi)
                                  : (hi == 0 ? wi :  wr);
            _Float16 v1 = (_Float16)v;
            _Float16 v2 = (_Float16)(v - (float)v1);
            h1[j] = v1; h2[j] = v2;
        }
    }
    *(f16x8*)(B1p + (size_t)t * 8) = h1;
    *(f16x8*)(B2p + (size_t)t * 8) = h2;
}

__global__ __launch_bounds__(TPB, 2) void beam_mfma(const float* __restrict__ x,
                                                    const _Float16* __restrict__ B1p,
                                                    const _Float16* __restrict__ B2p,
                                                    float* __restrict__ out) {
    // Phase 1: smem = B fragment buffer (64 KB).
    // Phase 2 (after barrier): smem = gains[64][GSTRIDE] + pout[64][PSTRIDE].
    __shared__ char smem[65536];
    _Float16* Bs = (_Float16*)smem;
    float* gl = (float*)smem;                       // 64*129 floats = 33024 B
    float* po = (float*)smem + 64 * GSTRIDE;        // 64*66 floats  = 16896 B

    const int tid = threadIdx.x;
    const int wave = tid >> 6;
    const int L = tid & 63;

    // ---- A fragments: wave handles rows mbase..mbase+15, K=128 in 4 steps.
    // fp16 split: x = a1 + a2 (exact to ~2^-24 rel).
    const int arow = blockIdx.x * 64 + wave * 16 + (L & 15);
    const float* xrow = x + (size_t)arow * 128;
    f16x8 a1[4], a2[4];
#pragma unroll
    for (int ks = 0; ks < 4; ++ks) {
        const int kb = ks * 32 + (L >> 4) * 8;
        float4 u = *(const float4*)(xrow + kb);
        float4 v = *(const float4*)(xrow + kb + 4);
        float xv[8] = {u.x, u.y, u.z, u.w, v.x, v.y, v.z, v.w};
#pragma unroll
        for (int j = 0; j < 8; ++j) {
            _Float16 p = (_Float16)xv[j];
            a1[ks][j] = p;
            a2[ks][j] = (_Float16)(xv[j] - (float)p);
        }
    }

    f32x4 acc[16];
#pragma unroll
    for (int nt = 0; nt < 16; ++nt) acc[nt] = (f32x4){0.f, 0.f, 0.f, 0.f};

    // ---- Stage B1, run terms A1*B1 and A2*B1 (B frag reused for both).
    {
        const float4* src = (const float4*)B1p;
        float4* dst = (float4*)smem;
#pragma unroll 4
        for (int i = tid; i < 4096; i += TPB) dst[i] = src[i];
    }
    __syncthreads();
#pragma unroll
    for (int nt = 0; nt < 16; ++nt) {
#pragma unroll
        for (int ks = 0; ks < 4; ++ks) {
            f16x8 b = *(const f16x8*)(Bs + (size_t)((nt * 4 + ks) * 64 + L) * 8);
            acc[nt] = __builtin_amdgcn_mfma_f32_16x16x32_f16(a1[ks], b, acc[nt], 0, 0, 0);
            acc[nt] = __builtin_amdgcn_mfma_f32_16x16x32_f16(a2[ks], b, acc[nt], 0, 0, 0);
        }
    }
    __syncthreads();

    // ---- Stage B2, run term A1*B2.
    {
        const float4* src = (const float4*)B2p;
        float4* dst = (float4*)smem;
#pragma unroll 4
        for (int i = tid; i < 4096; i += TPB) dst[i] = src[i];
    }
    __syncthreads();
#pragma unroll
    for (int nt = 0; nt < 16; ++nt) {
#pragma unroll
        for (int ks = 0; ks < 4; ++ks) {
            f16x8 b = *(const f16x8*)(Bs + (size_t)((nt * 4 + ks) * 64 + L) * 8);
            acc[nt] = __builtin_amdgcn_mfma_f32_16x16x32_f16(a1[ks], b, acc[nt], 0, 0, 0);
        }
    }
    __syncthreads();  // everyone done reading Bs before gains overwrite smem

    // ---- Gains: C layout col=lane&15, row=(lane>>4)*4+reg. Even col = y_re,
    // odd col = y_im of complex col c = (nt*16 + col)>>1. Pair via DPP lane^1.
#pragma unroll
    for (int nt = 0; nt < 16; ++nt) {
        const int cc = nt * 8 + ((L & 15) >> 1);
#pragma unroll
        for (int r = 0; r < 4; ++r) {
            float y = acc[nt][r];
            float yo = __int_as_float(__builtin_amdgcn_update_dpp(
                0, __float_as_int(y), 0xB1 /*quad_perm [1,0,3,2]*/, 0xF, 0xF, true));
            float gain = fmaf(y, y, yo * yo);
            const int el = wave * 16 + (L >> 4) * 4 + r;
            if ((L & 1) == 0 && cc < 126) gl[el * GSTRIDE + cc] = gain;
        }
    }
    __syncthreads();

    // ---- Softmax tree: 1 thread per element, register DFS stack (unrolled).
    if (tid < 64) {
        const float* g = gl + tid * GSTRIDE;
        float* pr = po + tid * PSTRIDE;
        float stk[10];
        int l = 0, n = 0, gi = 0;
#pragma unroll
        for (int s = 0; s < NSTEPS; ++s) {
            float g0 = g[2 * s];
            float g1 = g[2 * s + 1];
            float m  = fmaxf(g0, g1);
            float e0 = __expf(g0 - m);
            float e1 = __expf(g1 - m);
            float inv = fast_rcp(e0 + e1);
            float p0 = e0 * inv, p1 = e1 * inv;
            float pme = (l == 0) ? 1.0f : stk[(l - 1) * 2 + (n & 1)];
            if (l < 5) {
                stk[l * 2 + 0] = pme * p0;
                stk[l * 2 + 1] = pme * p1;
            } else {
                pr[2 * gi + 0] = pme * p0;
                pr[2 * gi + 1] = pme * p1;
                gi++;
            }
            dfs_next(l, n);
        }
    }
    __syncthreads();

    // ---- Coalesced flush: 64 rows x 64 floats = 16 KB contiguous.
    float4* ob = (float4*)(out + (size_t)blockIdx.x * 64 * 64);
#pragma unroll
    for (int q = 0; q < 4; ++q) {
        const int f = q * TPB + tid;     // float4 index in block tile
        const int row = f >> 4;          // 16 float4 per row
        const int col = (f & 15) * 4;
        const float* sp = po + row * PSTRIDE + col;
        v2f a = *(const v2f*)(sp);
        v2f b = *(const v2f*)(sp + 2);
        ob[f] = make_float4(a.x, a.y, b.x, b.y);
    }
}

extern "C" void kernel_launch(void* const* d_in, const int* in_sizes, int n_in,
                              void* d_out, int out_size, void* d_ws, size_t ws_size,
                              hipStream_t stream) {
    const float* x  = (const float*)d_in[0];
    const float* t0 = (const float*)d_in[1];
    const float* t1 = (const float*)d_in[2];
    const float* t2 = (const float*)d_in[3];
    const float* t3 = (const float*)d_in[4];
    const float* t4 = (const float*)d_in[5];
    _Float16* B1p = (_Float16*)d_ws;                      // 64 KB
    _Float16* B2p = (_Float16*)((char*)d_ws + 65536);     // 64 KB

    fill_B<<<dim3(16), dim3(256), 0, stream>>>(t0, t1, t2, t3, t4, B1p, B2p);
    beam_mfma<<<dim3(BATCH / 64), dim3(TPB), 0, stream>>>(x, B1p, B2p, (float*)d_out);
}